// Round 7
// baseline (142.975 us; speedup 1.0000x reference)
//
#include <hip/hip_runtime.h>

// EuclideanLoss: loss = (1/(B*N)) * sum_{b,n} w_n * sqrt(sum_d (x[b,n,d]-y[b,d,n])^2)
// w_n = 1.5 for n in {1,2}. B=32, N=8192, D=64, fp32. 128 MiB moved.
//
// R6: R5 confirmed the atomic-drain theory (64->42.6 us) but plateaued at
// ~3.1 TB/s effective with occupancy 24% and 80 vmem instrs/block.
// Changes: (1) y staged at 16 B/lane (1 KB/instr, 16 instrs/block vs 64) --
// m97's width-16 lesson; (2) x skips LDS: each thread loads its private 64 B
// slice as 4 float4 (L1-resident tile, no bank conflicts, no transpose need);
// (3) LDS 32->17 KB -> ~9 blocks/CU resident. y_s compute reads are
// uniform-d -> 2-way bank aliasing (free).

constexpr int B  = 32;
constexpr int N  = 8192;
constexpr int D  = 64;
constexpr int TN = 64;               // n per tile (block)
constexpr int NBLK = (N / TN) * B;   // 4096 partials

#define GLD_LDS16(gp, lp)                                                                \
    __builtin_amdgcn_global_load_lds(                                                    \
        (const __attribute__((address_space(1))) void*)(gp),                             \
        (__attribute__((address_space(3))) void*)(lp), 16, 0, 0)

__global__ __launch_bounds__(256) void euclid_loss_kernel(
    const float* __restrict__ x,   // [B, N, D]
    const float* __restrict__ y,   // [B, D, N]
    float* __restrict__ ws)        // [NBLK] per-block partials
{
    __shared__ float y_s[D * TN];   // [d][n], 16 KB, no padding (contiguous DMA)
    __shared__ float part[4][TN];   // 1 KB

    const int tid  = threadIdx.x;
    const int wave = tid >> 6;
    const int lane = tid & 63;
    const int n0   = blockIdx.x * TN;
    const int b    = blockIdx.y;

    // y: 64 rows x 256 B. One instr stages 1 KB = 4 rows: lane L covers
    // row d0 + L/16, bytes (L&15)*16 -- matches LDS dst base + L*16 exactly
    // because y_s rows (256 B) are contiguous.
    const float* yg = y + (size_t)b * D * N + n0;
#pragma unroll
    for (int i = 0; i < 4; ++i) {
        const int d0 = wave * 16 + i * 4;   // wave q stages rows q*16..q*16+15
        const float* gsrc = yg + (size_t)(d0 + (lane >> 4)) * N + (lane & 15) * 4;
        GLD_LDS16(gsrc, y_s + d0 * TN);
    }

    // x: thread (wave=q, lane=n) owns x[n0+lane][q*16 .. q*16+15] = 64 B,
    // read directly as 4 float4 (issued before the barrier, overlap staging).
    const float* xp = x + ((size_t)b * N + n0 + lane) * D + wave * 16;
    float4 xv[4];
#pragma unroll
    for (int j = 0; j < 4; ++j)
        xv[j] = *reinterpret_cast<const float4*>(xp + 4 * j);

    __syncthreads();   // vmcnt(0) drain: y_s staged, xv ready

    // d uniform per access -> y_s bank aliasing is 2-way (free).
    float acc = 0.0f;
#pragma unroll
    for (int j = 0; j < 4; ++j) {
        const int d = wave * 16 + j * 4;
        const float d0 = xv[j].x - y_s[(d + 0) * TN + lane];
        const float d1 = xv[j].y - y_s[(d + 1) * TN + lane];
        const float d2 = xv[j].z - y_s[(d + 2) * TN + lane];
        const float d3 = xv[j].w - y_s[(d + 3) * TN + lane];
        acc += d0 * d0 + d1 * d1 + d2 * d2 + d3 * d3;
    }

    part[wave][lane] = acc;
    __syncthreads();

    if (tid < TN) {
        const float s = part[0][tid] + part[1][tid] + part[2][tid] + part[3][tid];
        const int   n = n0 + tid;
        const float w = (n == 1 || n == 2) ? 1.5f : 1.0f;
        float v = w * __builtin_sqrtf(s);
#pragma unroll
        for (int off = 32; off > 0; off >>= 1) v += __shfl_down(v, off, 64);
        if (tid == 0)
            ws[blockIdx.y * gridDim.x + blockIdx.x] = v;   // plain store
    }
}

__global__ __launch_bounds__(256) void reduce_kernel(
    const float* __restrict__ ws,  // [NBLK]
    float* __restrict__ out)       // [1]
{
    const int tid = threadIdx.x;
    float v = 0.0f;
#pragma unroll
    for (int j = 0; j < NBLK / (256 * 4); ++j) {   // 4 float4 per thread
        const float4 p = *reinterpret_cast<const float4*>(ws + j * 1024 + tid * 4);
        v += p.x + p.y + p.z + p.w;
    }
#pragma unroll
    for (int off = 32; off > 0; off >>= 1) v += __shfl_down(v, off, 64);

    __shared__ float wsum[4];
    if ((tid & 63) == 0) wsum[tid >> 6] = v;
    __syncthreads();
    if (tid == 0)
        out[0] = (wsum[0] + wsum[1] + wsum[2] + wsum[3]) * (1.0f / (float)(B * N));
}

extern "C" void kernel_launch(void* const* d_in, const int* in_sizes, int n_in,
                              void* d_out, int out_size, void* d_ws, size_t ws_size,
                              hipStream_t stream) {
    const float* x = (const float*)d_in[0];
    const float* y = (const float*)d_in[1];
    float* out = (float*)d_out;
    float* ws  = (float*)d_ws;

    dim3 grid(N / TN, B);          // (128, 32) = 4096 blocks
    euclid_loss_kernel<<<grid, 256, 0, stream>>>(x, y, ws);
    reduce_kernel<<<1, 256, 0, stream>>>(ws, out);
}